// Round 11
// baseline (302.747 us; speedup 1.0000x reference)
//
#include <hip/hip_runtime.h>
#include <math.h>

#define BATCH 256
#define DIN   5120
#define RANK  160
#define NS    16
#define NCAT  192   // RANK + NS + NS
#define NSPLIT 40   // k-splits for k1 (chunk = 128)

// ---------------------------------------------------------------------------
// k1a: partial[z] = x(256x5120) @ [W_delta | W_B | W_C] over k-chunk z.
// Split-K (40 chunks of 128), 64x64 tile, 4x4 reg tile. NO atomics.
// (R6-proven, UNCHANGED.)
// ---------------------------------------------------------------------------
__global__ __launch_bounds__(256) void k1a_gemm(
    const float* __restrict__ x, const float* __restrict__ Wd,
    const float* __restrict__ WB, const float* __restrict__ WC,
    float* __restrict__ psum)
{
    __shared__ float xT[32][64];   // [k][m]
    __shared__ float Wt[32][64];   // [k][n]
    const int t  = threadIdx.x;
    const int m0 = blockIdx.x * 64;
    const int n0 = blockIdx.y * 64;
    const int z  = blockIdx.z;
    const int k0 = z * 128;
    const int tm = (t >> 4) * 4;
    const int tn = (t & 15) * 4;

    const int lm  = t >> 2;
    const int lk  = (t & 3) * 8;
    const int ln  = t & 63;
    const int lkb = (t >> 6) * 8;

    const float* wsrc; int wstr;
    {
        const int c = n0 + ln;
        if (c < RANK)            { wsrc = Wd + c;                wstr = RANK; }
        else if (c < RANK + NS)  { wsrc = WB + (c - RANK);       wstr = NS;   }
        else                     { wsrc = WC + (c - RANK - NS);  wstr = NS;   }
    }

    float acc[4][4] = {{0.f}};

    for (int ks = 0; ks < 4; ++ks) {
        const int kb = k0 + ks * 32;
        {
            const float* src = x + (size_t)(m0 + lm) * DIN + kb + lk;
            const float4 a0 = *(const float4*)src;
            const float4 a1 = *(const float4*)(src + 4);
            xT[lk+0][lm]=a0.x; xT[lk+1][lm]=a0.y; xT[lk+2][lm]=a0.z; xT[lk+3][lm]=a0.w;
            xT[lk+4][lm]=a1.x; xT[lk+5][lm]=a1.y; xT[lk+6][lm]=a1.z; xT[lk+7][lm]=a1.w;
        }
        {
            const float* wp = wsrc + (size_t)(kb + lkb) * wstr;
            #pragma unroll
            for (int i = 0; i < 8; ++i) { Wt[lkb + i][ln] = *wp; wp += wstr; }
        }
        __syncthreads();
        #pragma unroll
        for (int k = 0; k < 32; ++k) {
            const float4 a = *(const float4*)&xT[k][tm];
            const float4 b = *(const float4*)&Wt[k][tn];
            acc[0][0] += a.x*b.x; acc[0][1] += a.x*b.y; acc[0][2] += a.x*b.z; acc[0][3] += a.x*b.w;
            acc[1][0] += a.y*b.x; acc[1][1] += a.y*b.y; acc[1][2] += a.y*b.z; acc[1][3] += a.y*b.w;
            acc[2][0] += a.z*b.x; acc[2][1] += a.z*b.y; acc[2][2] += a.z*b.z; acc[2][3] += a.z*b.w;
            acc[3][0] += a.w*b.x; acc[3][1] += a.w*b.y; acc[3][2] += a.w*b.z; acc[3][3] += a.w*b.w;
        }
        __syncthreads();
    }

    float* dst = psum + (size_t)z * (BATCH * NCAT);
    #pragma unroll
    for (int i = 0; i < 4; ++i) {
        const int gm = m0 + tm + i;
        float4 o; o.x = acc[i][0]; o.y = acc[i][1]; o.z = acc[i][2]; o.w = acc[i][3];
        *(float4*)&dst[(size_t)gm * NCAT + n0 + tn] = o;
    }
}

// ---------------------------------------------------------------------------
// k1r: reduce 40 psum partials -> P/Bp/Cc. 192 blocks x 256 threads.
// (R6-proven, UNCHANGED.)
// ---------------------------------------------------------------------------
__global__ __launch_bounds__(256) void k1r_reduce(
    const float* __restrict__ psum,
    float* __restrict__ P, float* __restrict__ Bp, float* __restrict__ Cc)
{
    const int o = blockIdx.x * 256 + threadIdx.x; // 0..49151
    float s = 0.f;
    #pragma unroll 8
    for (int z = 0; z < NSPLIT; ++z) s += psum[(size_t)z * (BATCH * NCAT) + o];
    const int gm = o / NCAT;
    const int gc = o - gm * NCAT;
    if (gc < RANK)           P [gm * RANK + gc]             = s;
    else if (gc < RANK + NS) Bp[gm * NS   + gc - RANK]      = s;
    else                     Cc[gm * NS   + gc - RANK - NS] = s;
}

__device__ __forceinline__ float softplus20(float z)
{
    if (z > 20.f) return z;
    return fmaxf(z, 0.f) + log1pf(__expf(-fabsf(z)));
}

// ---------------------------------------------------------------------------
// k3_ssm: fused dt-GEMM + SSM. Grid (80,16): block = 64 channels x 16 batches.
// Phase A v4 (this round): SAME R6 structure, 2.5x fewer LDS reads —
//  (a) sP consumed 4 k at a time via broadcast ds_read_b128 (aligned: every
//      index term is a multiple of 4 floats); Bt reads stay scalar (2-way
//      bank alias = free). 800 -> 320 LDS reads/thread.
//  (b) dt never goes to LDS: each wave's phase-B batches are the ones whose
//      dt it computed, and dt[bl][q*16+j] is an intra-wave lane permutation
//      -> __shfl(sd, q*16+j) (VALU). sdt tile, 20 LDS ops/thread, and the
//      phase-A->B barrier all deleted (waves enter phase B independently).
// Phase B: R6-proven ILP structure, verbatim except the dtv source.
// ---------------------------------------------------------------------------
__global__ __launch_bounds__(256) void k3_ssm(
    const float* __restrict__ P, const float* __restrict__ Wdt,
    const float* __restrict__ bdt, const float* __restrict__ x,
    const float* __restrict__ h, const float* __restrict__ A_log,
    const float* __restrict__ Bp, const float* __restrict__ Cc,
    const float* __restrict__ Dv, float* __restrict__ y)
{
    __shared__ float sP[16 * RANK];   // 10 KB: P rows b0..b0+15, flat [b*160+k]
    __shared__ float Bt[32][64];      //  8 KB: Wdt k-tile

    const int t    = threadIdx.x;
    const int lane = t & 63;
    const int wv   = t >> 6;          // wave id
    const int c0   = blockIdx.x * 64; // 80 channel tiles
    const int b0   = blockIdx.y * 16; // 16 batch tiles

    // ---- phase A: dt for this wave's 4 batches, result in registers ----
    float sd0, sd1, sd2, sd3;
    {
        const float* Pb = P + (size_t)b0 * RANK;
        #pragma unroll
        for (int i = 0; i < 10; ++i) sP[i * 256 + t] = Pb[i * 256 + t];

        float acc[4] = {0.f, 0.f, 0.f, 0.f};
        const int r0 = (wv * 4 + 0) * RANK;
        const int r1 = (wv * 4 + 1) * RANK;
        const int r2 = (wv * 4 + 2) * RANK;
        const int r3 = (wv * 4 + 3) * RANK;

        for (int ks = 0; ks < 5; ++ks) {
            const int kb = ks * 32;
            {
                const float* wp = Wdt + (size_t)(kb + wv * 8) * DIN + c0 + lane;
                #pragma unroll
                for (int i = 0; i < 8; ++i) Bt[wv * 8 + i][lane] = wp[(size_t)i * DIN];
            }
            __syncthreads();
            #pragma unroll
            for (int k4 = 0; k4 < 32; k4 += 4) {
                const float w0 = Bt[k4 + 0][lane];
                const float w1 = Bt[k4 + 1][lane];
                const float w2 = Bt[k4 + 2][lane];
                const float w3 = Bt[k4 + 3][lane];
                const float4 a0 = *(const float4*)&sP[r0 + kb + k4];
                const float4 a1 = *(const float4*)&sP[r1 + kb + k4];
                const float4 a2 = *(const float4*)&sP[r2 + kb + k4];
                const float4 a3 = *(const float4*)&sP[r3 + kb + k4];
                acc[0] += a0.x*w0 + a0.y*w1 + a0.z*w2 + a0.w*w3;
                acc[1] += a1.x*w0 + a1.y*w1 + a1.z*w2 + a1.w*w3;
                acc[2] += a2.x*w0 + a2.y*w1 + a2.z*w2 + a2.w*w3;
                acc[3] += a3.x*w0 + a3.y*w1 + a3.z*w2 + a3.w*w3;
            }
            __syncthreads();
        }

        const float bz = bdt[c0 + lane];
        sd0 = softplus20(acc[0] + bz);
        sd1 = softplus20(acc[1] + bz);
        sd2 = softplus20(acc[2] + bz);
        sd3 = softplus20(acc[3] + bz);
    }
    // no barrier: each wave consumes only its own sd* registers below

    // ---- phase B: SSM update + readout (R6 verbatim; dtv via shfl) ----
    const int v = lane & 3;     // state quad: n = 4v..4v+3
    const int j = lane >> 2;    // channel within 16

    // per-lane channel constants: A2 = -log2(e)*exp(A_log) (16 per lane) + D
    float4 A2q[4]; float dvq[4];
    #pragma unroll
    for (int q = 0; q < 4; ++q) {
        const int c = c0 + q * 16 + j;
        const float4 al = *(const float4*)(A_log + (size_t)c * NS + v * 4);
        A2q[q].x = -1.442695041f * __expf(al.x);
        A2q[q].y = -1.442695041f * __expf(al.y);
        A2q[q].z = -1.442695041f * __expf(al.z);
        A2q[q].w = -1.442695041f * __expf(al.w);
        dvq[q] = Dv[c];
    }

    #pragma unroll
    for (int g = 0; g < 2; ++g) {
        const int gb0 = b0 + wv * 4 + g * 2;   // local batch pair
        const int gb1 = gb0 + 1;
        const float sdl = (g == 0) ? sd0 : sd2;   // dt row of batch gb0 (lane=chan)
        const float sdh = (g == 0) ? sd1 : sd3;   // dt row of batch gb1

        // h tile for (batch, c0..c0+63) = 1024 floats; q sub-block = q*256.
        const size_t hb0 = ((size_t)gb0 * DIN + c0) * NS;
        const size_t hb1 = ((size_t)gb1 * DIN + c0) * NS;
        const float4 h00 = *(const float4*)(h + hb0 +   0 + lane * 4);
        const float4 h01 = *(const float4*)(h + hb0 + 256 + lane * 4);
        const float4 h02 = *(const float4*)(h + hb0 + 512 + lane * 4);
        const float4 h03 = *(const float4*)(h + hb0 + 768 + lane * 4);
        const float4 h10 = *(const float4*)(h + hb1 +   0 + lane * 4);
        const float4 h11 = *(const float4*)(h + hb1 + 256 + lane * 4);
        const float4 h12 = *(const float4*)(h + hb1 + 512 + lane * 4);
        const float4 h13 = *(const float4*)(h + hb1 + 768 + lane * 4);
        const float  xr0 = x[(size_t)gb0 * DIN + c0 + lane];
        const float  xr1 = x[(size_t)gb1 * DIN + c0 + lane];
        const float4 B40 = *(const float4*)(Bp + gb0 * NS + v * 4);
        const float4 C40 = *(const float4*)(Cc + gb0 * NS + v * 4);
        const float4 B41 = *(const float4*)(Bp + gb1 * NS + v * 4);
        const float4 C41 = *(const float4*)(Cc + gb1 * NS + v * 4);

        // ---- batch 0 ----
        float res0[4];
        #pragma unroll
        for (int q = 0; q < 4; ++q) {
            const float dtv = __shfl(sdl, q * 16 + j, 64);
            const float xv  = __shfl(xr0, q * 16 + j, 64);
            const float dtx = dtv * xv;
            const float4 hv = (q == 0) ? h00 : (q == 1) ? h01 : (q == 2) ? h02 : h03;
            float s;
            s  = (exp2f(dtv * A2q[q].x) * hv.x + dtx * B40.x) * C40.x;
            s += (exp2f(dtv * A2q[q].y) * hv.y + dtx * B40.y) * C40.y;
            s += (exp2f(dtv * A2q[q].z) * hv.z + dtx * B40.z) * C40.z;
            s += (exp2f(dtv * A2q[q].w) * hv.w + dtx * B40.w) * C40.w;
            if (v == 0) s += xv * dvq[q];
            res0[q] = s;
        }

        // ---- batch 1 ----
        float res1[4];
        #pragma unroll
        for (int q = 0; q < 4; ++q) {
            const float dtv = __shfl(sdh, q * 16 + j, 64);
            const float xv  = __shfl(xr1, q * 16 + j, 64);
            const float dtx = dtv * xv;
            const float4 hv = (q == 0) ? h10 : (q == 1) ? h11 : (q == 2) ? h12 : h13;
            float s;
            s  = (exp2f(dtv * A2q[q].x) * hv.x + dtx * B41.x) * C41.x;
            s += (exp2f(dtv * A2q[q].y) * hv.y + dtx * B41.y) * C41.y;
            s += (exp2f(dtv * A2q[q].z) * hv.z + dtx * B41.z) * C41.z;
            s += (exp2f(dtv * A2q[q].w) * hv.w + dtx * B41.w) * C41.w;
            if (v == 0) s += xv * dvq[q];
            res1[q] = s;
        }

        // ---- 4-lane n-sum + coalesced stores ----
        #pragma unroll
        for (int q = 0; q < 4; ++q) {
            res0[q] += __shfl_xor(res0[q], 1, 64);
            res0[q] += __shfl_xor(res0[q], 2, 64);
            res1[q] += __shfl_xor(res1[q], 1, 64);
            res1[q] += __shfl_xor(res1[q], 2, 64);
        }
        const float out0 = (v == 0) ? res0[0] : (v == 1) ? res0[1]
                         : (v == 2) ? res0[2] : res0[3];
        const float out1 = (v == 0) ? res1[0] : (v == 1) ? res1[1]
                         : (v == 2) ? res1[2] : res1[3];
        y[(size_t)gb0 * DIN + c0 + v * 16 + j] = out0;
        y[(size_t)gb1 * DIN + c0 + v * 16 + j] = out1;
    }
}

// ---------------------------------------------------------------------------
extern "C" void kernel_launch(void* const* d_in, const int* in_sizes, int n_in,
                              void* d_out, int out_size, void* d_ws, size_t ws_size,
                              hipStream_t stream)
{
    const float* x     = (const float*)d_in[0];
    const float* h     = (const float*)d_in[1];
    const float* Wd    = (const float*)d_in[2];
    const float* Wdt   = (const float*)d_in[3];
    const float* bdt   = (const float*)d_in[4];
    const float* A_log = (const float*)d_in[5];
    const float* WB    = (const float*)d_in[6];
    const float* WC    = (const float*)d_in[7];
    const float* Dv    = (const float*)d_in[8];
    float* out = (float*)d_out;

    // ws layout (floats): psum (40x256x192 = 7.9 MB) | P (256x160) | Bp | Cc
    float* psum = (float*)d_ws;
    float* P    = psum + (size_t)NSPLIT * BATCH * NCAT;
    float* Bp   = P  + BATCH * RANK;
    float* Cc   = Bp + BATCH * NS;

    // no memset needed: every ws word is written before it is read
    k1a_gemm  <<<dim3(4, 3, NSPLIT), 256, 0, stream>>>(x, Wd, WB, WC, psum);
    k1r_reduce<<<dim3(NCAT),         256, 0, stream>>>(psum, P, Bp, Cc);
    k3_ssm    <<<dim3(80, 16),       256, 0, stream>>>(P, Wdt, bdt, x, h, A_log,
                                                       Bp, Cc, Dv, out);
}

// Round 12
// 172.608 us; speedup vs baseline: 1.7540x; 1.7540x over previous
//
#include <hip/hip_runtime.h>
#include <math.h>

#define BATCH 256
#define DIN   5120
#define RANK  160
#define NS    16
#define NCAT  192   // RANK + NS + NS
#define NSPLIT 40   // k-splits for k1 (chunk = 128)

// ---------------------------------------------------------------------------
// k1a: partial[z] = x(256x5120) @ [W_delta | W_B | W_C] over k-chunk z.
// Split-K (40 chunks of 128), 64x64 tile, 4x4 reg tile. NO atomics.
// (R6-proven, UNCHANGED.)
// ---------------------------------------------------------------------------
__global__ __launch_bounds__(256) void k1a_gemm(
    const float* __restrict__ x, const float* __restrict__ Wd,
    const float* __restrict__ WB, const float* __restrict__ WC,
    float* __restrict__ psum)
{
    __shared__ float xT[32][64];   // [k][m]
    __shared__ float Wt[32][64];   // [k][n]
    const int t  = threadIdx.x;
    const int m0 = blockIdx.x * 64;
    const int n0 = blockIdx.y * 64;
    const int z  = blockIdx.z;
    const int k0 = z * 128;
    const int tm = (t >> 4) * 4;
    const int tn = (t & 15) * 4;

    const int lm  = t >> 2;
    const int lk  = (t & 3) * 8;
    const int ln  = t & 63;
    const int lkb = (t >> 6) * 8;

    const float* wsrc; int wstr;
    {
        const int c = n0 + ln;
        if (c < RANK)            { wsrc = Wd + c;                wstr = RANK; }
        else if (c < RANK + NS)  { wsrc = WB + (c - RANK);       wstr = NS;   }
        else                     { wsrc = WC + (c - RANK - NS);  wstr = NS;   }
    }

    float acc[4][4] = {{0.f}};

    for (int ks = 0; ks < 4; ++ks) {
        const int kb = k0 + ks * 32;
        {
            const float* src = x + (size_t)(m0 + lm) * DIN + kb + lk;
            const float4 a0 = *(const float4*)src;
            const float4 a1 = *(const float4*)(src + 4);
            xT[lk+0][lm]=a0.x; xT[lk+1][lm]=a0.y; xT[lk+2][lm]=a0.z; xT[lk+3][lm]=a0.w;
            xT[lk+4][lm]=a1.x; xT[lk+5][lm]=a1.y; xT[lk+6][lm]=a1.z; xT[lk+7][lm]=a1.w;
        }
        {
            const float* wp = wsrc + (size_t)(kb + lkb) * wstr;
            #pragma unroll
            for (int i = 0; i < 8; ++i) { Wt[lkb + i][ln] = *wp; wp += wstr; }
        }
        __syncthreads();
        #pragma unroll
        for (int k = 0; k < 32; ++k) {
            const float4 a = *(const float4*)&xT[k][tm];
            const float4 b = *(const float4*)&Wt[k][tn];
            acc[0][0] += a.x*b.x; acc[0][1] += a.x*b.y; acc[0][2] += a.x*b.z; acc[0][3] += a.x*b.w;
            acc[1][0] += a.y*b.x; acc[1][1] += a.y*b.y; acc[1][2] += a.y*b.z; acc[1][3] += a.y*b.w;
            acc[2][0] += a.z*b.x; acc[2][1] += a.z*b.y; acc[2][2] += a.z*b.z; acc[2][3] += a.z*b.w;
            acc[3][0] += a.w*b.x; acc[3][1] += a.w*b.y; acc[3][2] += a.w*b.z; acc[3][3] += a.w*b.w;
        }
        __syncthreads();
    }

    float* dst = psum + (size_t)z * (BATCH * NCAT);
    #pragma unroll
    for (int i = 0; i < 4; ++i) {
        const int gm = m0 + tm + i;
        float4 o; o.x = acc[i][0]; o.y = acc[i][1]; o.z = acc[i][2]; o.w = acc[i][3];
        *(float4*)&dst[(size_t)gm * NCAT + n0 + tn] = o;
    }
}

// ---------------------------------------------------------------------------
// k1r: reduce 40 psum partials -> P/Bp/Cc. 192 blocks x 256 threads.
// (R6-proven, UNCHANGED.)
// ---------------------------------------------------------------------------
__global__ __launch_bounds__(256) void k1r_reduce(
    const float* __restrict__ psum,
    float* __restrict__ P, float* __restrict__ Bp, float* __restrict__ Cc)
{
    const int o = blockIdx.x * 256 + threadIdx.x; // 0..49151
    float s = 0.f;
    #pragma unroll 8
    for (int z = 0; z < NSPLIT; ++z) s += psum[(size_t)z * (BATCH * NCAT) + o];
    const int gm = o / NCAT;
    const int gc = o - gm * NCAT;
    if (gc < RANK)           P [gm * RANK + gc]             = s;
    else if (gc < RANK + NS) Bp[gm * NS   + gc - RANK]      = s;
    else                     Cc[gm * NS   + gc - RANK - NS] = s;
}

__device__ __forceinline__ float softplus20(float z)
{
    if (z > 20.f) return z;
    return fmaxf(z, 0.f) + log1pf(__expf(-fabsf(z)));
}

// ---------------------------------------------------------------------------
// k3_ssm: fused dt-GEMM + SSM. Grid (80,16): block = 64 channels x 16 batches.
// R6 structure EXACTLY (sdt LDS tile, phase-A->B barrier kept as scheduler
// fence — R8/R10/R11 lesson: cross-phase live-range growth => 256-VGPR spill).
// Single change vs R6: phase-A inner loop consumes sP 4 k at a time via
// broadcast ds_read_b128 (aligned: r*160 + kb + k4 all multiples of 4 floats).
// Phase-A LDS issues/thread: ~800 -> ~320. Bt reads stay scalar (2-way bank
// alias = free). Phase B byte-identical to R6.
// ---------------------------------------------------------------------------
__global__ __launch_bounds__(256) void k3_ssm(
    const float* __restrict__ P, const float* __restrict__ Wdt,
    const float* __restrict__ bdt, const float* __restrict__ x,
    const float* __restrict__ h, const float* __restrict__ A_log,
    const float* __restrict__ Bp, const float* __restrict__ Cc,
    const float* __restrict__ Dv, float* __restrict__ y)
{
    __shared__ __align__(16) float sP[16 * RANK];  // 10 KB: P rows, flat [b*160+k]
    __shared__ float Bt[32][64];      //  8 KB: Wdt k-tile
    __shared__ float sdt[16][64];     //  4 KB: dt tile [b_local][c_local]

    const int t    = threadIdx.x;
    const int lane = t & 63;
    const int wv   = t >> 6;          // wave id
    const int c0   = blockIdx.x * 64; // 80 channel tiles
    const int b0   = blockIdx.y * 16; // 16 batch tiles

    // ---- phase A: dt tile (M=16 batches, N=64 channels, K=160) ----
    {
        const float* Pb = P + (size_t)b0 * RANK;
        #pragma unroll
        for (int i = 0; i < 10; ++i) sP[i * 256 + t] = Pb[i * 256 + t];

        float acc[4] = {0.f, 0.f, 0.f, 0.f};
        const int r0 = (wv * 4 + 0) * RANK;
        const int r1 = (wv * 4 + 1) * RANK;
        const int r2 = (wv * 4 + 2) * RANK;
        const int r3 = (wv * 4 + 3) * RANK;

        for (int ks = 0; ks < 5; ++ks) {
            const int kb = ks * 32;
            {
                const float* wp = Wdt + (size_t)(kb + wv * 8) * DIN + c0 + lane;
                #pragma unroll
                for (int i = 0; i < 8; ++i) Bt[wv * 8 + i][lane] = wp[(size_t)i * DIN];
            }
            __syncthreads();
            #pragma unroll
            for (int k4 = 0; k4 < 32; k4 += 4) {
                const float w0 = Bt[k4 + 0][lane];
                const float w1 = Bt[k4 + 1][lane];
                const float w2 = Bt[k4 + 2][lane];
                const float w3 = Bt[k4 + 3][lane];
                const float4 a0 = *(const float4*)&sP[r0 + kb + k4];
                const float4 a1 = *(const float4*)&sP[r1 + kb + k4];
                const float4 a2 = *(const float4*)&sP[r2 + kb + k4];
                const float4 a3 = *(const float4*)&sP[r3 + kb + k4];
                acc[0] += a0.x*w0 + a0.y*w1 + a0.z*w2 + a0.w*w3;
                acc[1] += a1.x*w0 + a1.y*w1 + a1.z*w2 + a1.w*w3;
                acc[2] += a2.x*w0 + a2.y*w1 + a2.z*w2 + a2.w*w3;
                acc[3] += a3.x*w0 + a3.y*w1 + a3.z*w2 + a3.w*w3;
            }
            __syncthreads();
        }

        const float bz = bdt[c0 + lane];
        #pragma unroll
        for (int i = 0; i < 4; ++i)
            sdt[wv * 4 + i][lane] = softplus20(acc[i] + bz);
    }
    __syncthreads();

    // ---- phase B: SSM update + readout (R6 verbatim) ----
    const int v = lane & 3;     // state quad: n = 4v..4v+3
    const int j = lane >> 2;    // channel within 16

    // per-lane channel constants: A2 = -log2(e)*exp(A_log) (16 per lane) + D
    float4 A2q[4]; float dvq[4];
    #pragma unroll
    for (int q = 0; q < 4; ++q) {
        const int c = c0 + q * 16 + j;
        const float4 al = *(const float4*)(A_log + (size_t)c * NS + v * 4);
        A2q[q].x = -1.442695041f * __expf(al.x);
        A2q[q].y = -1.442695041f * __expf(al.y);
        A2q[q].z = -1.442695041f * __expf(al.z);
        A2q[q].w = -1.442695041f * __expf(al.w);
        dvq[q] = Dv[c];
    }

    #pragma unroll
    for (int g = 0; g < 2; ++g) {
        const int bl0 = wv * 4 + g * 2;     // local batch pair
        const int gb0 = b0 + bl0;
        const int gb1 = gb0 + 1;

        // h tile for (batch, c0..c0+63) = 1024 floats; q sub-block = q*256.
        const size_t hb0 = ((size_t)gb0 * DIN + c0) * NS;
        const size_t hb1 = ((size_t)gb1 * DIN + c0) * NS;
        const float4 h00 = *(const float4*)(h + hb0 +   0 + lane * 4);
        const float4 h01 = *(const float4*)(h + hb0 + 256 + lane * 4);
        const float4 h02 = *(const float4*)(h + hb0 + 512 + lane * 4);
        const float4 h03 = *(const float4*)(h + hb0 + 768 + lane * 4);
        const float4 h10 = *(const float4*)(h + hb1 +   0 + lane * 4);
        const float4 h11 = *(const float4*)(h + hb1 + 256 + lane * 4);
        const float4 h12 = *(const float4*)(h + hb1 + 512 + lane * 4);
        const float4 h13 = *(const float4*)(h + hb1 + 768 + lane * 4);
        const float  xr0 = x[(size_t)gb0 * DIN + c0 + lane];
        const float  xr1 = x[(size_t)gb1 * DIN + c0 + lane];
        const float4 B40 = *(const float4*)(Bp + gb0 * NS + v * 4);
        const float4 C40 = *(const float4*)(Cc + gb0 * NS + v * 4);
        const float4 B41 = *(const float4*)(Bp + gb1 * NS + v * 4);
        const float4 C41 = *(const float4*)(Cc + gb1 * NS + v * 4);

        // ---- batch 0 ----
        float res0[4];
        #pragma unroll
        for (int q = 0; q < 4; ++q) {
            const float dtv = sdt[bl0][q * 16 + j];
            const float xv  = __shfl(xr0, q * 16 + j, 64);
            const float dtx = dtv * xv;
            const float4 hv = (q == 0) ? h00 : (q == 1) ? h01 : (q == 2) ? h02 : h03;
            float s;
            s  = (exp2f(dtv * A2q[q].x) * hv.x + dtx * B40.x) * C40.x;
            s += (exp2f(dtv * A2q[q].y) * hv.y + dtx * B40.y) * C40.y;
            s += (exp2f(dtv * A2q[q].z) * hv.z + dtx * B40.z) * C40.z;
            s += (exp2f(dtv * A2q[q].w) * hv.w + dtx * B40.w) * C40.w;
            if (v == 0) s += xv * dvq[q];
            res0[q] = s;
        }

        // ---- batch 1 ----
        float res1[4];
        #pragma unroll
        for (int q = 0; q < 4; ++q) {
            const float dtv = sdt[bl0 + 1][q * 16 + j];
            const float xv  = __shfl(xr1, q * 16 + j, 64);
            const float dtx = dtv * xv;
            const float4 hv = (q == 0) ? h10 : (q == 1) ? h11 : (q == 2) ? h12 : h13;
            float s;
            s  = (exp2f(dtv * A2q[q].x) * hv.x + dtx * B41.x) * C41.x;
            s += (exp2f(dtv * A2q[q].y) * hv.y + dtx * B41.y) * C41.y;
            s += (exp2f(dtv * A2q[q].z) * hv.z + dtx * B41.z) * C41.z;
            s += (exp2f(dtv * A2q[q].w) * hv.w + dtx * B41.w) * C41.w;
            if (v == 0) s += xv * dvq[q];
            res1[q] = s;
        }

        // ---- 4-lane n-sum + coalesced stores ----
        #pragma unroll
        for (int q = 0; q < 4; ++q) {
            res0[q] += __shfl_xor(res0[q], 1, 64);
            res0[q] += __shfl_xor(res0[q], 2, 64);
            res1[q] += __shfl_xor(res1[q], 1, 64);
            res1[q] += __shfl_xor(res1[q], 2, 64);
        }
        const float out0 = (v == 0) ? res0[0] : (v == 1) ? res0[1]
                         : (v == 2) ? res0[2] : res0[3];
        const float out1 = (v == 0) ? res1[0] : (v == 1) ? res1[1]
                         : (v == 2) ? res1[2] : res1[3];
        y[(size_t)gb0 * DIN + c0 + v * 16 + j] = out0;
        y[(size_t)gb1 * DIN + c0 + v * 16 + j] = out1;
    }
}

// ---------------------------------------------------------------------------
extern "C" void kernel_launch(void* const* d_in, const int* in_sizes, int n_in,
                              void* d_out, int out_size, void* d_ws, size_t ws_size,
                              hipStream_t stream)
{
    const float* x     = (const float*)d_in[0];
    const float* h     = (const float*)d_in[1];
    const float* Wd    = (const float*)d_in[2];
    const float* Wdt   = (const float*)d_in[3];
    const float* bdt   = (const float*)d_in[4];
    const float* A_log = (const float*)d_in[5];
    const float* WB    = (const float*)d_in[6];
    const float* WC    = (const float*)d_in[7];
    const float* Dv    = (const float*)d_in[8];
    float* out = (float*)d_out;

    // ws layout (floats): psum (40x256x192 = 7.9 MB) | P (256x160) | Bp | Cc
    float* psum = (float*)d_ws;
    float* P    = psum + (size_t)NSPLIT * BATCH * NCAT;
    float* Bp   = P  + BATCH * RANK;
    float* Cc   = Bp + BATCH * NS;

    // no memset needed: every ws word is written before it is read
    k1a_gemm  <<<dim3(4, 3, NSPLIT), 256, 0, stream>>>(x, Wd, WB, WC, psum);
    k1r_reduce<<<dim3(NCAT),         256, 0, stream>>>(psum, P, Bp, Cc);
    k3_ssm    <<<dim3(80, 16),       256, 0, stream>>>(P, Wdt, bdt, x, h, A_log,
                                                       Bp, Cc, Dv, out);
}